// Round 4
// baseline (156.176 us; speedup 1.0000x reference)
//
#include <hip/hip_runtime.h>
#include <hip/hip_bf16.h>
#include <cstdint>
#include <cstddef>

// SelfAttention fused block, MI355X gfx950.
// Round 3: attention kv-split. No-max softmax => unnormalized O and lsum are
// LINEAR in the kv-tile set, so 2 waves split one q-tile's kv range
// (even/odd tiles) and merge by simple addition via LDS at the end.
// 2x wave count (1024 blocks, 4/CU), half the per-wave serial chain.
//   K1: x fp32 -> bf16; K2: W transpose-convert; K3: gemm_bt<1> qkv proj;
//   K4: flash attention (32x32 swapped-QK^T, in-register softmax);
//   K5: gemm_bt<0> out proj.

using bf16 = __hip_bfloat16;
typedef __attribute__((ext_vector_type(8))) short short8;
typedef __attribute__((ext_vector_type(4))) float f32x4;
typedef __attribute__((ext_vector_type(16))) float f32x16;
typedef __attribute__((ext_vector_type(4))) unsigned int u32x4;

__device__ __forceinline__ unsigned short f2b(float f) {
    bf16 h = __float2bfloat16(f);
    return *reinterpret_cast<unsigned short*>(&h);
}

__device__ __forceinline__ void async16(const void* g, void* l) {
    __builtin_amdgcn_global_load_lds(
        (const __attribute__((address_space(1))) void*)g,
        (__attribute__((address_space(3))) void*)l, 16, 0, 0);
}

// ---------------- K1: fp32 -> bf16 elementwise (float4 / ushort4) ------------
__global__ __launch_bounds__(256) void cvt_kernel(const float* __restrict__ in,
                                                  bf16* __restrict__ out, int n4) {
    int i = blockIdx.x * 256 + threadIdx.x;
    if (i >= n4) return;
    const float4 v = reinterpret_cast<const float4*>(in)[i];
    ushort4 o;
    o.x = f2b(v.x); o.y = f2b(v.y); o.z = f2b(v.z); o.w = f2b(v.w);
    reinterpret_cast<ushort4*>(out)[i] = o;
}

// ---------------- K2: in fp32 [K][N] -> out bf16 [N][K] ----------------------
__global__ __launch_bounds__(256) void transpose_cvt(const float* __restrict__ in,
                                                     bf16* __restrict__ out,
                                                     int K, int N) {
    __shared__ float tile[32][33];
    int n0 = blockIdx.x * 32, k0 = blockIdx.y * 32;
    int tx = threadIdx.x, ty = threadIdx.y;  // (32,8)
    #pragma unroll
    for (int i = 0; i < 32; i += 8)
        tile[ty + i][tx] = in[(size_t)(k0 + ty + i) * N + n0 + tx];
    __syncthreads();
    #pragma unroll
    for (int i = 0; i < 32; i += 8)
        out[(size_t)(n0 + ty + i) * K + k0 + tx] = __float2bfloat16(tile[tx][ty + i]);
}

// ---------------- K3/K5: 128x128x32 bf16 MFMA GEMM, B^T input ----------------
template <int EPI>
__global__ __launch_bounds__(256) void gemm_bt(
    const bf16* __restrict__ A,   // [M][K] bf16
    const bf16* __restrict__ Bt,  // [N][K] bf16
    const float* __restrict__ bias,  // [N] fp32
    float* __restrict__ Cf,          // EPI==0: [M][N] fp32
    bf16* __restrict__ qd, bf16* __restrict__ kd, bf16* __restrict__ vtd,
    int M, int N, int K) {
    __shared__ bf16 As[128 * 32];
    __shared__ bf16 Bs[128 * 32];
    const int t = threadIdx.x;
    const int lane = t & 63;
    const int lr = lane & 15, lg = lane >> 4;
    const int wave = t >> 6;
    const int wr = wave >> 1, wc = wave & 1;  // 2x2 waves of 64x64
    const int m0 = blockIdx.x * 128, n0 = blockIdx.y * 128;

    const bf16* aSrc = A + (size_t)(m0 + (t >> 2)) * K + (t & 3) * 8;
    const bf16* bSrc = Bt + (size_t)(n0 + (t >> 2)) * K + (t & 3) * 8;
    bf16* aDst0 = &As[t * 8];
    bf16* aDst1 = &As[2048 + t * 8];
    bf16* bDst0 = &Bs[t * 8];
    bf16* bDst1 = &Bs[2048 + t * 8];
    const size_t rowStep = (size_t)64 * K;

    f32x4 acc[4][4] = {};

    for (int k0 = 0; k0 < K; k0 += 32) {
        __syncthreads();
        async16(aSrc + k0, aDst0);
        async16(aSrc + rowStep + k0, aDst1);
        async16(bSrc + k0, bDst0);
        async16(bSrc + rowStep + k0, bDst1);
        __syncthreads();
        short8 af[4], bfr[4];
        #pragma unroll
        for (int i = 0; i < 4; ++i)
            af[i] = *reinterpret_cast<const short8*>(
                &As[(wr * 64 + i * 16 + lr) * 32 + lg * 8]);
        #pragma unroll
        for (int i = 0; i < 4; ++i)
            bfr[i] = *reinterpret_cast<const short8*>(
                &Bs[(wc * 64 + i * 16 + lr) * 32 + lg * 8]);
        #pragma unroll
        for (int mi = 0; mi < 4; ++mi)
            #pragma unroll
            for (int ni = 0; ni < 4; ++ni)
                acc[mi][ni] = __builtin_amdgcn_mfma_f32_16x16x32_bf16(
                    af[mi], bfr[ni], acc[mi][ni], 0, 0, 0);
    }

    #pragma unroll
    for (int mi = 0; mi < 4; ++mi) {
        #pragma unroll
        for (int ni = 0; ni < 4; ++ni) {
            #pragma unroll
            for (int r = 0; r < 4; ++r) {
                const int row = m0 + wr * 64 + mi * 16 + lg * 4 + r;
                const int col = n0 + wc * 64 + ni * 16 + lr;
                const float v = acc[mi][ni][r] + bias[col];
                if constexpr (EPI == 0) {
                    Cf[(size_t)row * N + col] = v;
                } else {
                    const bf16 hv = __float2bfloat16(v);
                    const int part = col >> 10;      // 0=q 1=k 2=v
                    const int within = col & 1023;
                    const int h = within >> 6, d = within & 63;
                    const int b = row >> 11, s = row & 2047;
                    const int bh = b * 16 + h;
                    if (part == 0)
                        qd[((size_t)bh * 2048 + s) * 64 + d] = hv;
                    else if (part == 1)
                        kd[((size_t)bh * 2048 + s) * 64 + d] = hv;
                    else
                        vtd[((size_t)bh * 64 + d) * 2048 + s] = hv;
                }
            }
        }
    }
}

// ---------------- K4: causal flash attention, 32x32 swapped-QK^T, kv-split ---
// grid (32, B*H), block 256 = 4 waves = 2 PAIRS. Pair 0 (waves 0,1) owns
// q-tile 63-bx; pair 1 (waves 2,3) owns q-tile bx (block totals constant=65).
// Within a pair, wave parity p takes kv-tiles tt===p (mod 2) below the
// diagonal; diagonal (masked) tile goes to parity qt&1 (balances counts).
// Merge: partial O and lsum ADD (no-max softmax is linear) via LDS + 1 barrier.
__global__ __launch_bounds__(256, 4) void attn_kernel(const bf16* __restrict__ q,
                                                      const bf16* __restrict__ k,
                                                      const bf16* __restrict__ vt,
                                                      bf16* __restrict__ o) {
    const int S = 2048;
    const int bh = blockIdx.y;
    const int b = bh >> 4, h = bh & 15;
    const int w = threadIdx.x >> 6;
    const int lane = threadIdx.x & 63;
    const int ln = lane & 31;   // q index (QK) / d index (PV) / A-row
    const int hi = lane >> 5;   // half-wave
    const int bx = blockIdx.x;  // 0..31
    const int pair = w >> 1;
    const int p = w & 1;
    const int qt = pair ? bx : (63 - bx);
    const int qbase = qt * 32;

    const bf16* qp = q + (size_t)bh * S * 64;
    const bf16* kp = k + (size_t)bh * S * 64;
    const bf16* vp = vt + (size_t)bh * 64 * S;

    // Q B-frags (rows = q): qf[i] = Q[qbase+ln][i*16 + hi*8 + 0..7]
    short8 qf[4];
    #pragma unroll
    for (int i = 0; i < 4; ++i)
        qf[i] = *reinterpret_cast<const short8*>(
            &qp[(size_t)(qbase + ln) * 64 + i * 16 + hi * 8]);

    f32x16 oacc0 = {}, oacc1 = {};  // O[q][d0..31], O[q][d32..63] (partial)
    float lsum = 0.f;

    short8 kA[4], kB[4], vA[4], vB[4];

    auto kload = [&](short8 (&kf)[4], int tile) {
        const bf16* base = &kp[(size_t)(tile * 32 + ln) * 64 + hi * 8];
        #pragma unroll
        for (int i = 0; i < 4; ++i)
            kf[i] = *reinterpret_cast<const short8*>(base + i * 16);
    };
    auto vload = [&](short8 (&vf)[4], int tile) {
        #pragma unroll
        for (int dblk = 0; dblk < 2; ++dblk)
            #pragma unroll
            for (int half = 0; half < 2; ++half)
                vf[dblk * 2 + half] = *reinterpret_cast<const short8*>(
                    &vp[(size_t)(dblk * 32 + ln) * S + tile * 32 + half * 16 +
                        hi * 8]);
    };

    auto body = [&](short8 (&kf)[4], short8 (&vf)[4], bool diag) {
        f32x16 z0 = {}, z1 = {};
        z0 = __builtin_amdgcn_mfma_f32_32x32x16_bf16(kf[0], qf[0], z0, 0, 0, 0);
        z0 = __builtin_amdgcn_mfma_f32_32x32x16_bf16(kf[1], qf[1], z0, 0, 0, 0);
        z1 = __builtin_amdgcn_mfma_f32_32x32x16_bf16(kf[2], qf[2], z1, 0, 0, 0);
        z1 = __builtin_amdgcn_mfma_f32_32x32x16_bf16(kf[3], qf[3], z1, 0, 0, 0);
        const f32x16 z = z0 + z1;
        f32x16 pv;
        #pragma unroll
        for (int r = 0; r < 16; ++r) {
            const int kreg = (r & 3) + 8 * (r >> 2) + 4 * hi;
            float e = __expf(z[r] * 0.125f);
            if (diag && (kreg > ln)) e = 0.f;
            pv[r] = e;
            lsum += e;
        }
        unsigned a0, a1, b0, b1, c0, c1, d0, d1;
        asm("v_cvt_pk_bf16_f32 %0, %1, %2" : "=v"(a0) : "v"(pv[0]), "v"(pv[1]));
        asm("v_cvt_pk_bf16_f32 %0, %1, %2" : "=v"(a1) : "v"(pv[2]), "v"(pv[3]));
        asm("v_cvt_pk_bf16_f32 %0, %1, %2" : "=v"(b0) : "v"(pv[4]), "v"(pv[5]));
        asm("v_cvt_pk_bf16_f32 %0, %1, %2" : "=v"(b1) : "v"(pv[6]), "v"(pv[7]));
        asm("v_cvt_pk_bf16_f32 %0, %1, %2" : "=v"(c0) : "v"(pv[8]), "v"(pv[9]));
        asm("v_cvt_pk_bf16_f32 %0, %1, %2" : "=v"(c1) : "v"(pv[10]), "v"(pv[11]));
        asm("v_cvt_pk_bf16_f32 %0, %1, %2" : "=v"(d0) : "v"(pv[12]), "v"(pv[13]));
        asm("v_cvt_pk_bf16_f32 %0, %1, %2" : "=v"(d1) : "v"(pv[14]), "v"(pv[15]));
        asm("v_permlane32_swap_b32 %0, %1" : "+v"(a0), "+v"(b0));
        asm("v_permlane32_swap_b32 %0, %1" : "+v"(a1), "+v"(b1));
        asm("v_permlane32_swap_b32 %0, %1" : "+v"(c0), "+v"(d0));
        asm("v_permlane32_swap_b32 %0, %1" : "+v"(c1), "+v"(d1));
        u32x4 t0, t1;
        t0[0] = a0; t0[1] = a1; t0[2] = b0; t0[3] = b1;   // P[q][kv 0..15]
        t1[0] = c0; t1[1] = c1; t1[2] = d0; t1[3] = d1;   // P[q][kv 16..31]
        const short8 pa0 = __builtin_bit_cast(short8, t0);
        const short8 pa1 = __builtin_bit_cast(short8, t1);
        oacc0 = __builtin_amdgcn_mfma_f32_32x32x16_bf16(pa0, vf[0], oacc0, 0, 0, 0);
        oacc0 = __builtin_amdgcn_mfma_f32_32x32x16_bf16(pa1, vf[1], oacc0, 0, 0, 0);
        oacc1 = __builtin_amdgcn_mfma_f32_32x32x16_bf16(pa0, vf[2], oacc1, 0, 0, 0);
        oacc1 = __builtin_amdgcn_mfma_f32_32x32x16_bf16(pa1, vf[3], oacc1, 0, 0, 0);
    };

    // ---- this wave's kv-tile list: p, p+2, ... < qt, then diag if owner ----
    const int nfull = (qt - p + 1) >> 1;
    const bool owner = ((qt & 1) == p);
    const int n = nfull + (owner ? 1 : 0);
    auto tileAt = [&](int i) { return (i < nfull) ? (p + 2 * i) : qt; };

    if (n > 0) {
        kload(kA, tileAt(0));
        vload(vA, tileAt(0));
        for (int i = 0; i + 1 < n; ++i) {
            kload(kB, tileAt(i + 1));
            vload(vB, tileAt(i + 1));
            body(kA, vA, false);
            #pragma unroll
            for (int j = 0; j < 4; ++j) { kA[j] = kB[j]; vA[j] = vB[j]; }
        }
        body(kA, vA, owner);
    }

    // ---- pair merge: partial O and lsum add via LDS (once per kernel) ----
    __shared__ float red[2][64 * 32];
    __shared__ float redl[2][64];
    if (p == 1) {
        float* dst = &red[pair][lane * 32];
        #pragma unroll
        for (int r = 0; r < 16; ++r) { dst[r] = oacc0[r]; dst[16 + r] = oacc1[r]; }
        redl[pair][lane] = lsum;
    }
    __syncthreads();
    if (p == 1) return;
    {
        const float* src = &red[pair][lane * 32];
        #pragma unroll
        for (int r = 0; r < 16; ++r) { oacc0[r] += src[r]; oacc1[r] += src[16 + r]; }
        lsum += redl[pair][lane];
    }

    // ---- finalize: row-sum across lane halves, normalize, store ----
    lsum += __shfl_xor(lsum, 32, 64);
    const float myInv = 1.0f / lsum;  // for q = qbase + ln
    #pragma unroll
    for (int r = 0; r < 16; ++r) {
        const int qrow = (r & 3) + 8 * (r >> 2) + 4 * hi;
        const float inv = __shfl(myInv, qrow, 64);
        const int qq = qbase + qrow;
        const size_t rowOff = ((size_t)b * S + qq) * 1024 + h * 64;
        o[rowOff + ln] = __float2bfloat16(oacc0[r] * inv);
        o[rowOff + 32 + ln] = __float2bfloat16(oacc1[r] * inv);
    }
}

// -----------------------------------------------------------------------------
extern "C" void kernel_launch(void* const* d_in, const int* in_sizes, int n_in,
                              void* d_out, int out_size, void* d_ws, size_t ws_size,
                              hipStream_t stream) {
    const float* x = (const float*)d_in[0];     // [2,2048,1024]
    const float* Wqkv = (const float*)d_in[1];  // [1024,3072]
    const float* bqkv = (const float*)d_in[2];  // [3072]
    const float* Wo = (const float*)d_in[3];    // [1024,1024]
    const float* bo = (const float*)d_in[4];    // [1024]
    float* out = (float*)d_out;                 // [2,2048,1024] fp32
    char* ws = (char*)d_ws;

    // workspace layout (bytes), total 40 MB
    bf16* x_bf = (bf16*)(ws);                  //  8388608  [4096][1024]
    bf16* wqkv_t = (bf16*)(ws + 8388608);      //  6291456  [3072][1024]
    bf16* wo_t = (bf16*)(ws + 14680064);       //  2097152  [1024][1024]
    bf16* qb = (bf16*)(ws + 16777216);         //  8388608  [2,16,2048,64]
    bf16* kb = (bf16*)(ws + 25165824);         //  8388608  [2,16,2048,64]
    bf16* vtb = (bf16*)(ws + 33554432);        //  8388608  [2,16,64,2048]
    bf16* attn_o = x_bf;                       // alias: x_bf dead after gemm1

    cvt_kernel<<<4096, 256, 0, stream>>>(x, x_bf, 1048576);
    transpose_cvt<<<dim3(96, 32), dim3(32, 8), 0, stream>>>(Wqkv, wqkv_t, 1024, 3072);
    transpose_cvt<<<dim3(32, 32), dim3(32, 8), 0, stream>>>(Wo, wo_t, 1024, 1024);
    gemm_bt<1><<<dim3(32, 24), 256, 0, stream>>>(x_bf, wqkv_t, bqkv, nullptr, qb, kb,
                                                 vtb, 4096, 3072, 1024);
    attn_kernel<<<dim3(32, 32), 256, 0, stream>>>(qb, kb, vtb, attn_o);
    gemm_bt<0><<<dim3(32, 8), 256, 0, stream>>>(attn_o, wo_t, bo, out, nullptr,
                                                nullptr, nullptr, 4096, 1024, 1024);
}

// Round 5
// 129.000 us; speedup vs baseline: 1.2107x; 1.2107x over previous
//
#include <hip/hip_runtime.h>
#include <hip/hip_bf16.h>
#include <cstdint>
#include <cstddef>

// SelfAttention fused block, MI355X gfx950.
// Round 4: attention locality + intensity rewrite.
//  - XCD-aware 1-D grid swizzle: heads {r,r+8,r+16,r+24} -> XCD r, so each
//    XCD's private 4MB L2 holds its 4 heads' Q/K/V (3MB). Kills HBM re-fetch.
//  - 2 q-tiles (64 q-rows) per wave share one K/V fragment stream: halves
//    logical K/V traffic, doubles per-iter independent chains (ILP).
//  - kv parity split across wave pairs + LDS merge (padded rows: 65 floats,
//    2-way bank = free). Vector lsum accumulators (no serial fp-add chain).
//  - complementary block pairing: CU's two blocks sum to constant work.
//   K1: x fp32 -> bf16; K2: W transpose-convert; K3: gemm_bt<1> qkv proj;
//   K4: flash attention; K5: gemm_bt<0> out proj.

using bf16 = __hip_bfloat16;
typedef __attribute__((ext_vector_type(8))) short short8;
typedef __attribute__((ext_vector_type(4))) float f32x4;
typedef __attribute__((ext_vector_type(16))) float f32x16;
typedef __attribute__((ext_vector_type(4))) unsigned int u32x4;

__device__ __forceinline__ unsigned short f2b(float f) {
    bf16 h = __float2bfloat16(f);
    return *reinterpret_cast<unsigned short*>(&h);
}

__device__ __forceinline__ void async16(const void* g, void* l) {
    __builtin_amdgcn_global_load_lds(
        (const __attribute__((address_space(1))) void*)g,
        (__attribute__((address_space(3))) void*)l, 16, 0, 0);
}

// ---------------- K1: fp32 -> bf16 elementwise (float4 / ushort4) ------------
__global__ __launch_bounds__(256) void cvt_kernel(const float* __restrict__ in,
                                                  bf16* __restrict__ out, int n4) {
    int i = blockIdx.x * 256 + threadIdx.x;
    if (i >= n4) return;
    const float4 v = reinterpret_cast<const float4*>(in)[i];
    ushort4 o;
    o.x = f2b(v.x); o.y = f2b(v.y); o.z = f2b(v.z); o.w = f2b(v.w);
    reinterpret_cast<ushort4*>(out)[i] = o;
}

// ---------------- K2: in fp32 [K][N] -> out bf16 [N][K] ----------------------
__global__ __launch_bounds__(256) void transpose_cvt(const float* __restrict__ in,
                                                     bf16* __restrict__ out,
                                                     int K, int N) {
    __shared__ float tile[32][33];
    int n0 = blockIdx.x * 32, k0 = blockIdx.y * 32;
    int tx = threadIdx.x, ty = threadIdx.y;  // (32,8)
    #pragma unroll
    for (int i = 0; i < 32; i += 8)
        tile[ty + i][tx] = in[(size_t)(k0 + ty + i) * N + n0 + tx];
    __syncthreads();
    #pragma unroll
    for (int i = 0; i < 32; i += 8)
        out[(size_t)(n0 + ty + i) * K + k0 + tx] = __float2bfloat16(tile[tx][ty + i]);
}

// ---------------- K3/K5: 128x128x32 bf16 MFMA GEMM, B^T input ----------------
template <int EPI>
__global__ __launch_bounds__(256) void gemm_bt(
    const bf16* __restrict__ A,   // [M][K] bf16
    const bf16* __restrict__ Bt,  // [N][K] bf16
    const float* __restrict__ bias,  // [N] fp32
    float* __restrict__ Cf,          // EPI==0: [M][N] fp32
    bf16* __restrict__ qd, bf16* __restrict__ kd, bf16* __restrict__ vtd,
    int M, int N, int K) {
    __shared__ bf16 As[128 * 32];
    __shared__ bf16 Bs[128 * 32];
    const int t = threadIdx.x;
    const int lane = t & 63;
    const int lr = lane & 15, lg = lane >> 4;
    const int wave = t >> 6;
    const int wr = wave >> 1, wc = wave & 1;  // 2x2 waves of 64x64
    const int m0 = blockIdx.x * 128, n0 = blockIdx.y * 128;

    const bf16* aSrc = A + (size_t)(m0 + (t >> 2)) * K + (t & 3) * 8;
    const bf16* bSrc = Bt + (size_t)(n0 + (t >> 2)) * K + (t & 3) * 8;
    bf16* aDst0 = &As[t * 8];
    bf16* aDst1 = &As[2048 + t * 8];
    bf16* bDst0 = &Bs[t * 8];
    bf16* bDst1 = &Bs[2048 + t * 8];
    const size_t rowStep = (size_t)64 * K;

    f32x4 acc[4][4] = {};

    for (int k0 = 0; k0 < K; k0 += 32) {
        __syncthreads();
        async16(aSrc + k0, aDst0);
        async16(aSrc + rowStep + k0, aDst1);
        async16(bSrc + k0, bDst0);
        async16(bSrc + rowStep + k0, bDst1);
        __syncthreads();
        short8 af[4], bfr[4];
        #pragma unroll
        for (int i = 0; i < 4; ++i)
            af[i] = *reinterpret_cast<const short8*>(
                &As[(wr * 64 + i * 16 + lr) * 32 + lg * 8]);
        #pragma unroll
        for (int i = 0; i < 4; ++i)
            bfr[i] = *reinterpret_cast<const short8*>(
                &Bs[(wc * 64 + i * 16 + lr) * 32 + lg * 8]);
        #pragma unroll
        for (int mi = 0; mi < 4; ++mi)
            #pragma unroll
            for (int ni = 0; ni < 4; ++ni)
                acc[mi][ni] = __builtin_amdgcn_mfma_f32_16x16x32_bf16(
                    af[mi], bfr[ni], acc[mi][ni], 0, 0, 0);
    }

    #pragma unroll
    for (int mi = 0; mi < 4; ++mi) {
        #pragma unroll
        for (int ni = 0; ni < 4; ++ni) {
            #pragma unroll
            for (int r = 0; r < 4; ++r) {
                const int row = m0 + wr * 64 + mi * 16 + lg * 4 + r;
                const int col = n0 + wc * 64 + ni * 16 + lr;
                const float v = acc[mi][ni][r] + bias[col];
                if constexpr (EPI == 0) {
                    Cf[(size_t)row * N + col] = v;
                } else {
                    const bf16 hv = __float2bfloat16(v);
                    const int part = col >> 10;      // 0=q 1=k 2=v
                    const int within = col & 1023;
                    const int h = within >> 6, d = within & 63;
                    const int b = row >> 11, s = row & 2047;
                    const int bh = b * 16 + h;
                    if (part == 0)
                        qd[((size_t)bh * 2048 + s) * 64 + d] = hv;
                    else if (part == 1)
                        kd[((size_t)bh * 2048 + s) * 64 + d] = hv;
                    else
                        vtd[((size_t)bh * 64 + d) * 2048 + s] = hv;
                }
            }
        }
    }
}

// ---------------- K4: causal flash attention ---------------------------------
// grid 512 (1-D, XCD-swizzled), block 256 = 4 waves = 2 units x 2 parities.
// Decode: res=f&7, m=f>>3, grp=m>>4, bh=res+8*grp, bxr=m&15,
//         bx = (grp&2) ? 15-bxr : bxr   (CU's 2 blocks have complementary work)
// Unit u (waves 2u,2u+1) owns q-pair P=2*(15-bx)+u: q-tiles qtA=2P, qtB=2P+1
// (64 q-rows). Both q-tiles share each K/V fragment load (2x intensity).
// Wave parity `par` processes kv-tiles t===par (mod 2), t<=2P+1.
// Merge partial O/lsum across parities via padded LDS (linear, no-max softmax).
__global__ __launch_bounds__(256, 2) void attn_kernel(const bf16* __restrict__ q,
                                                      const bf16* __restrict__ k,
                                                      const bf16* __restrict__ vt,
                                                      bf16* __restrict__ o) {
    const int S = 2048;
    const int f = blockIdx.x;
    const int res = f & 7, m = f >> 3;
    const int grp = m >> 4;
    const int bh = res + 8 * grp;
    const int bxr = m & 15;
    const int bx = (grp & 2) ? (15 - bxr) : bxr;
    const int b = bh >> 4, h = bh & 15;
    const int w = threadIdx.x >> 6;
    const int u = w >> 1, par = w & 1;
    const int lane = threadIdx.x & 63;
    const int ln = lane & 31;
    const int hi = lane >> 5;
    const int P = 2 * (15 - bx) + u;     // 0..31
    const int qbaseA = P * 64;
    const int qbaseB = P * 64 + 32;

    const bf16* qp = q + (size_t)bh * S * 64;
    const bf16* kp = k + (size_t)bh * S * 64;
    const bf16* vp = vt + (size_t)bh * 64 * S;

    // Q B-frags for both q-tiles: qf[i] = Q[qbase+ln][i*16 + hi*8 + 0..7]
    short8 qfA[4], qfB[4];
    #pragma unroll
    for (int i = 0; i < 4; ++i) {
        qfA[i] = *reinterpret_cast<const short8*>(
            &qp[(size_t)(qbaseA + ln) * 64 + i * 16 + hi * 8]);
        qfB[i] = *reinterpret_cast<const short8*>(
            &qp[(size_t)(qbaseB + ln) * 64 + i * 16 + hi * 8]);
    }

    f32x16 oA0 = {}, oA1 = {}, oB0 = {}, oB1 = {};
    f32x4 lsvA = {0.f, 0.f, 0.f, 0.f}, lsvB = {0.f, 0.f, 0.f, 0.f};

    short8 kA[4], kB[4], vA[4], vB[4];

    auto kload = [&](short8 (&kf)[4], int tile) {
        const bf16* base = &kp[(size_t)(tile * 32 + ln) * 64 + hi * 8];
        #pragma unroll
        for (int i = 0; i < 4; ++i)
            kf[i] = *reinterpret_cast<const short8*>(base + i * 16);
    };
    auto vload = [&](short8 (&vf)[4], int tile) {
        #pragma unroll
        for (int dblk = 0; dblk < 2; ++dblk)
            #pragma unroll
            for (int half = 0; half < 2; ++half)
                vf[dblk * 2 + half] = *reinterpret_cast<const short8*>(
                    &vp[(size_t)(dblk * 32 + ln) * S + tile * 32 + half * 16 +
                        hi * 8]);
    };

    // one q-tile body against one kv-tile (frags shared by caller)
    auto body = [&](const short8 (&kf)[4], const short8 (&vf)[4],
                    const short8 (&qf)[4], f32x16& o0, f32x16& o1, f32x4& lsv,
                    bool diag) {
        f32x16 z0 = {}, z1 = {};
        z0 = __builtin_amdgcn_mfma_f32_32x32x16_bf16(kf[0], qf[0], z0, 0, 0, 0);
        z0 = __builtin_amdgcn_mfma_f32_32x32x16_bf16(kf[1], qf[1], z0, 0, 0, 0);
        z1 = __builtin_amdgcn_mfma_f32_32x32x16_bf16(kf[2], qf[2], z1, 0, 0, 0);
        z1 = __builtin_amdgcn_mfma_f32_32x32x16_bf16(kf[3], qf[3], z1, 0, 0, 0);
        const f32x16 z = z0 + z1;
        f32x16 pv;
        #pragma unroll
        for (int r = 0; r < 16; ++r) {
            const int kreg = (r & 3) + 8 * (r >> 2) + 4 * hi;
            float e = __expf(z[r] * 0.125f);
            if (diag && (kreg > ln)) e = 0.f;
            pv[r] = e;
            lsv[r & 3] += e;
        }
        unsigned a0, a1, b0, b1, c0, c1, d0, d1;
        asm("v_cvt_pk_bf16_f32 %0, %1, %2" : "=v"(a0) : "v"(pv[0]), "v"(pv[1]));
        asm("v_cvt_pk_bf16_f32 %0, %1, %2" : "=v"(a1) : "v"(pv[2]), "v"(pv[3]));
        asm("v_cvt_pk_bf16_f32 %0, %1, %2" : "=v"(b0) : "v"(pv[4]), "v"(pv[5]));
        asm("v_cvt_pk_bf16_f32 %0, %1, %2" : "=v"(b1) : "v"(pv[6]), "v"(pv[7]));
        asm("v_cvt_pk_bf16_f32 %0, %1, %2" : "=v"(c0) : "v"(pv[8]), "v"(pv[9]));
        asm("v_cvt_pk_bf16_f32 %0, %1, %2" : "=v"(c1) : "v"(pv[10]), "v"(pv[11]));
        asm("v_cvt_pk_bf16_f32 %0, %1, %2" : "=v"(d0) : "v"(pv[12]), "v"(pv[13]));
        asm("v_cvt_pk_bf16_f32 %0, %1, %2" : "=v"(d1) : "v"(pv[14]), "v"(pv[15]));
        asm("v_permlane32_swap_b32 %0, %1" : "+v"(a0), "+v"(b0));
        asm("v_permlane32_swap_b32 %0, %1" : "+v"(a1), "+v"(b1));
        asm("v_permlane32_swap_b32 %0, %1" : "+v"(c0), "+v"(d0));
        asm("v_permlane32_swap_b32 %0, %1" : "+v"(c1), "+v"(d1));
        u32x4 t0, t1;
        t0[0] = a0; t0[1] = a1; t0[2] = b0; t0[3] = b1;   // P[q][kv 0..15]
        t1[0] = c0; t1[1] = c1; t1[2] = d0; t1[3] = d1;   // P[q][kv 16..31]
        const short8 pa0 = __builtin_bit_cast(short8, t0);
        const short8 pa1 = __builtin_bit_cast(short8, t1);
        o0 = __builtin_amdgcn_mfma_f32_32x32x16_bf16(pa0, vf[0], o0, 0, 0, 0);
        o0 = __builtin_amdgcn_mfma_f32_32x32x16_bf16(pa1, vf[1], o0, 0, 0, 0);
        o1 = __builtin_amdgcn_mfma_f32_32x32x16_bf16(pa0, vf[2], o1, 0, 0, 0);
        o1 = __builtin_amdgcn_mfma_f32_32x32x16_bf16(pa1, vf[3], o1, 0, 0, 0);
    };

    auto dual = [&](const short8 (&kf)[4], const short8 (&vf)[4]) {
        body(kf, vf, qfA, oA0, oA1, lsvA, false);
        body(kf, vf, qfB, oB0, oB1, lsvB, false);
    };
    auto final_body = [&](const short8 (&kf)[4], const short8 (&vf)[4]) {
        if (par == 0) {  // t == 2P: diag for A, full for B
            body(kf, vf, qfA, oA0, oA1, lsvA, true);
            body(kf, vf, qfB, oB0, oB1, lsvB, false);
        } else {         // t == 2P+1: diag for B only
            body(kf, vf, qfB, oB0, oB1, lsvB, true);
        }
    };

    // ---- main loop over this parity's kv tiles: t = par + 2*i, i = 0..P ----
    kload(kA, par);
    vload(vA, par);
    int i = 0;
    for (; i + 2 <= P; i += 2) {
        kload(kB, par + 2 * (i + 1));
        vload(vB, par + 2 * (i + 1));
        dual(kA, vA);
        kload(kA, par + 2 * (i + 2));
        vload(vA, par + 2 * (i + 2));
        dual(kB, vB);
    }
    if (i < P) {  // i == P-1
        kload(kB, par + 2 * P);
        vload(vB, par + 2 * P);
        dual(kA, vA);
        final_body(kB, vB);
    } else {      // i == P
        final_body(kA, vA);
    }

    // ---- collapse lsum vectors to scalars ----
    float lsA = (lsvA[0] + lsvA[1]) + (lsvA[2] + lsvA[3]);
    float lsB = (lsvB[0] + lsvB[1]) + (lsvB[2] + lsvB[3]);

    // ---- parity merge via LDS (padded rows: 65 floats => 2-way, free) ----
    __shared__ float red[2][64][65];
    __shared__ float redl[2][64][2];
    if (par == 1) {
        float* dst = red[u][lane];
        #pragma unroll
        for (int r = 0; r < 16; ++r) {
            dst[r] = oA0[r];
            dst[16 + r] = oA1[r];
            dst[32 + r] = oB0[r];
            dst[48 + r] = oB1[r];
        }
        redl[u][lane][0] = lsA;
        redl[u][lane][1] = lsB;
    }
    __syncthreads();
    if (par == 1) return;
    {
        const float* src = red[u][lane];
        #pragma unroll
        for (int r = 0; r < 16; ++r) {
            oA0[r] += src[r];
            oA1[r] += src[16 + r];
            oB0[r] += src[32 + r];
            oB1[r] += src[48 + r];
        }
        lsA += redl[u][lane][0];
        lsB += redl[u][lane][1];
    }

    // ---- finalize: sum lane halves, normalize, store both q-tiles ----
    lsA += __shfl_xor(lsA, 32, 64);
    lsB += __shfl_xor(lsB, 32, 64);
    const float myInvA = 1.0f / lsA;  // valid for q = qbaseA + ln
    const float myInvB = 1.0f / lsB;
    #pragma unroll
    for (int r = 0; r < 16; ++r) {
        const int qrow = (r & 3) + 8 * (r >> 2) + 4 * hi;
        const float invA = __shfl(myInvA, qrow, 64);
        const float invB = __shfl(myInvB, qrow, 64);
        const size_t rowA = ((size_t)b * S + qbaseA + qrow) * 1024 + h * 64;
        const size_t rowB = ((size_t)b * S + qbaseB + qrow) * 1024 + h * 64;
        o[rowA + ln] = __float2bfloat16(oA0[r] * invA);
        o[rowA + 32 + ln] = __float2bfloat16(oA1[r] * invA);
        o[rowB + ln] = __float2bfloat16(oB0[r] * invB);
        o[rowB + 32 + ln] = __float2bfloat16(oB1[r] * invB);
    }
}

// -----------------------------------------------------------------------------
extern "C" void kernel_launch(void* const* d_in, const int* in_sizes, int n_in,
                              void* d_out, int out_size, void* d_ws, size_t ws_size,
                              hipStream_t stream) {
    const float* x = (const float*)d_in[0];     // [2,2048,1024]
    const float* Wqkv = (const float*)d_in[1];  // [1024,3072]
    const float* bqkv = (const float*)d_in[2];  // [3072]
    const float* Wo = (const float*)d_in[3];    // [1024,1024]
    const float* bo = (const float*)d_in[4];    // [1024]
    float* out = (float*)d_out;                 // [2,2048,1024] fp32
    char* ws = (char*)d_ws;

    // workspace layout (bytes), total 40 MB
    bf16* x_bf = (bf16*)(ws);                  //  8388608  [4096][1024]
    bf16* wqkv_t = (bf16*)(ws + 8388608);      //  6291456  [3072][1024]
    bf16* wo_t = (bf16*)(ws + 14680064);       //  2097152  [1024][1024]
    bf16* qb = (bf16*)(ws + 16777216);         //  8388608  [2,16,2048,64]
    bf16* kb = (bf16*)(ws + 25165824);         //  8388608  [2,16,2048,64]
    bf16* vtb = (bf16*)(ws + 33554432);        //  8388608  [2,16,64,2048]
    bf16* attn_o = x_bf;                       // alias: x_bf dead after gemm1

    cvt_kernel<<<4096, 256, 0, stream>>>(x, x_bf, 1048576);
    transpose_cvt<<<dim3(96, 32), dim3(32, 8), 0, stream>>>(Wqkv, wqkv_t, 1024, 3072);
    transpose_cvt<<<dim3(32, 32), dim3(32, 8), 0, stream>>>(Wo, wo_t, 1024, 1024);
    gemm_bt<1><<<dim3(32, 24), 256, 0, stream>>>(x_bf, wqkv_t, bqkv, nullptr, qb, kb,
                                                 vtb, 4096, 3072, 1024);
    attn_kernel<<<512, 256, 0, stream>>>(qb, kb, vtb, attn_o);
    gemm_bt<0><<<dim3(32, 8), 256, 0, stream>>>(attn_o, wo_t, bo, out, nullptr,
                                                nullptr, nullptr, 4096, 1024, 1024);
}